// Round 9
// baseline (170.070 us; speedup 1.0000x reference)
//
#include <hip/hip_runtime.h>
#include <hip/hip_bf16.h>
#include <stdint.h>

#define B_ 64
#define N_ 1024
#define E_ 16384
#define F_ 128
#define H_ 64
#define T_ 10
#define BN (B_*N_)   // 65536
#define BE (B_*E_)   // 1048576
#define SLOTS 24     // per-quarter per-node capacity (lambda=4, P(overflow)~1e-14)

// sigmoid(z) >= p  <=>  z >= log(p/(1-p))
#define TH_INNER (-0.84729786f)   // logit(0.3)
#define TH_CROSS (-2.1972246f)    // logit(0.1)

typedef __attribute__((ext_vector_type(8))) short short8;  // bf16x8 MFMA frag
typedef __attribute__((ext_vector_type(4))) float f32x4;   // MFMA acc

__device__ __forceinline__ float ld1(const void* p, int i, int bf) {
    if (bf) {
        uint16_t u = ((const uint16_t*)p)[i];
        return __uint_as_float(((uint32_t)u) << 16);
    }
    return ((const float*)p)[i];
}

__device__ __forceinline__ short to_bf(float x) {
    return (short)__bfloat16_as_ushort(__float2bfloat16(x));
}

__device__ __forceinline__ uint32_t pack_bf2(float lo, float hi) {
    uint32_t l = (uint32_t)__bfloat16_as_ushort(__float2bfloat16(lo));
    uint32_t h = (uint32_t)__bfloat16_as_ushort(__float2bfloat16(hi));
    return l | (h << 16);
}

__device__ __forceinline__ float bflo(uint32_t u) { return __uint_as_float(u << 16); }
__device__ __forceinline__ float bfhi(uint32_t u) { return __uint_as_float(u & 0xffff0000u); }

// ---- launch 1: count + scatter (fixed-stride quarter buckets, no scan) + fused W-prep ----
__global__ __launch_bounds__(1024) void k_csp(const int* __restrict__ src,
                                              const int* __restrict__ dst,
                                              int* __restrict__ bucket4,
                                              int* __restrict__ cnt4t,
                                              const void* __restrict__ W1,
                                              const void* __restrict__ W2,
                                              const void* __restrict__ tokens,
                                              int* __restrict__ flag,
                                              short8* __restrict__ Bfr,
                                              short8* __restrict__ Bfr2,
                                              float* __restrict__ gsum,
                                              int* __restrict__ done,
                                              uint32_t* __restrict__ y1pad,
                                              uint32_t* __restrict__ y2pad) {
    __shared__ int lcnt[N_];
    int t = threadIdx.x;
    if (blockIdx.x >= 256) {                     // fused k_prep (blocks 256,257)
        uint32_t du = ((const uint32_t*)tokens)[t & 63];
        float dlo = __uint_as_float(du << 16);
        unsigned long long vote = __ballot(fabsf(dlo) <= 1.0f);
        int bf = (vote == ~0ull) ? 1 : 0;
        if (blockIdx.x == 256 && t == 0) *flag = bf;
        int f = (int)(blockIdx.x - 256) * 1024 + t;   // [0, 2048)
        if (f < 1280) {                          // Bfr: [128 x 80] = W1 | tokens^T
            int c = f / 320, rem = f % 320;
            int nt = rem / 64, lane = rem % 64;
            int q = lane >> 4, n = nt * 16 + (lane & 15);
            int k0 = c * 32 + q * 8;
            short8 v;
#pragma unroll
            for (int j = 0; j < 8; ++j) {
                int k = k0 + j;
                float x = 0.f;
                if (n < H_) x = ld1(W1, k * H_ + n, bf);
                else if (n < H_ + T_) x = ld1(tokens, (n - H_) * F_ + k, bf);
                v[j] = to_bf(x);
            }
            Bfr[f] = v;
        } else if (f < 1792) {                   // Bfr2: W2 [64 x 64]
            int f2 = f - 1280;
            int c = f2 / 256, rem = f2 % 256;
            int nt = rem / 64, lane = rem % 64;
            int q = lane >> 4, n = nt * 16 + (lane & 15);
            int k0 = c * 32 + q * 8;
            short8 v;
#pragma unroll
            for (int j = 0; j < 8; ++j) v[j] = to_bf(ld1(W2, (k0 + j) * H_ + n, bf));
            Bfr2[f2] = v;
        }
        return;
    }
    int g = blockIdx.x & 63, c = blockIdx.x >> 6;   // 4 quarter-blocks per graph
    lcnt[t] = 0;
    if (c == 0 && t < 64) gsum[g * 64 + t] = 0.f;   // zero pool row
    if (blockIdx.x == 0) {                          // zero pad rows + tickets once
        if (t < 32) y1pad[t] = 0;
        else if (t < 64) y2pad[t - 32] = 0;
        else if (t >= 128 && t < 192) done[t - 128] = 0;
    }
    __syncthreads();
    int dval[4], sval[4];                            // edges cached in VGPRs
#pragma unroll
    for (int it = 0; it < 4; ++it) {
        int i = g * E_ + c * 4096 + it * 1024 + t;
        dval[it] = dst[i];
        sval[it] = src[i];
        atomicAdd(&lcnt[dval[it]], 1);
    }
    __syncthreads();
    cnt4t[(g * N_ + t) * 4 + c] = min(lcnt[t], SLOTS);
    lcnt[t] = 0;                                     // reuse as slot cursor
    __syncthreads();
#pragma unroll
    for (int it = 0; it < 4; ++it) {
        int d = dval[it];
        int p = atomicAdd(&lcnt[d], 1);
        if (p < SLOTS)
            bucket4[(size_t)(g * N_ + d) * (4 * SLOTS) + c * SLOTS + p] = g * N_ + sval[it];
    }
}

// ---- launch 2: node GEMM (blocks 0..255) | tok (block 256) ----
__global__ __launch_bounds__(1024) void k_node_tok(const void* __restrict__ x,
                                                   const short8* __restrict__ Bfr,
                                                   const short8* __restrict__ Bfr2,
                                                   const int* __restrict__ cnt4t,
                                                   const int* __restrict__ flag,
                                                   const void* __restrict__ tokens,
                                                   const void* __restrict__ b1,
                                                   const void* __restrict__ b2,
                                                   uint32_t* __restrict__ y1,
                                                   uint32_t* __restrict__ y2,
                                                   float* __restrict__ tok_sum,
                                                   float* __restrict__ inv_s,
                                                   int* __restrict__ maskA) {
    __shared__ float nm[T_ * 16];
    __shared__ float ist_s[16], idt_s[16];
    __shared__ float htbuf[T_ * 64];
    __shared__ float h1s[T_ * 64];
    int t = threadIdx.x;
    int bf = *flag;
    if (blockIdx.x < 256) {                      // ---- node GEMM ----
        int lane = t & 63, w16 = t >> 6;
        int g = blockIdx.x & 63, c = blockIdx.x >> 6;   // XCD swizzle
        int row0 = g * N_ + c * 256 + w16 * 16;
        int m = lane & 15, q = lane >> 4;
        int row = row0 + m;
        short8 afr[4];
        if (bf) {
            const short8* ar = (const short8*)((const uint16_t*)x + (size_t)row * F_);
#pragma unroll
            for (int cc = 0; cc < 4; ++cc) afr[cc] = ar[cc * 4 + q];
        } else {
            const float* ar = (const float*)x + (size_t)row * F_;
#pragma unroll
            for (int cc = 0; cc < 4; ++cc)
#pragma unroll
                for (int j = 0; j < 8; ++j)
                    afr[cc][j] = to_bf(ar[cc * 32 + q * 8 + j]);
        }
        f32x4 acc[5] = {};
#pragma unroll
        for (int nt = 0; nt < 5; ++nt)
#pragma unroll
            for (int cc = 0; cc < 4; ++cc) {
                short8 bfr = Bfr[(cc * 5 + nt) * 64 + lane];
                acc[nt] = __builtin_amdgcn_mfma_f32_16x16x32_bf16(afr[cc], bfr, acc[nt], 0, 0, 0);
            }
        unsigned long long bal[4];
#pragma unroll
        for (int r = 0; r < 4; ++r) {
            int pred = (m < T_) && (acc[4][r] >= TH_CROSS);
            bal[r] = __ballot(pred);
        }
        float isv[4];
#pragma unroll
        for (int r = 0; r < 4; ++r) {
            int node = row0 + q * 4 + r;
            int mk = (int)((bal[r] >> (q * 16)) & 0x3FF);
            uint4 c4 = *(const uint4*)&cnt4t[node * 4];
            int ec = (int)(c4.x + c4.y + c4.z + c4.w);
            int pc = __popc((unsigned)mk);
            float deg = 1.f + (float)ec + (float)pc;
            isv[r] = 1.f / sqrtf(deg);
            if (m == 0) { inv_s[node] = isv[r]; maskA[node] = mk; }
        }
#pragma unroll
        for (int r = 0; r < 4; ++r) {
            int node = row0 + q * 4 + r;
#pragma unroll
            for (int nt = 0; nt < 4; ++nt) {
                float v = acc[nt][r] * isv[r];
                float vh = __shfl(v, lane + 1);
                if ((m & 1) == 0)
                    y1[(size_t)node * 32 + nt * 8 + (m >> 1)] = pack_bf2(v, vh);
            }
        }
        return;
    }
    // ---- tok path (block 256): wave 0 computes, all waves share barriers ----
    int l = t;
    bool act = (l < 64);                         // wave-uniform guard
    int m = l & 15, q = (l & 63) >> 4;
    int mrow = (m < T_) ? m : (T_ - 1);
    f32x4 accM = {};
    f32x4 acc1[4] = {};
    float istc = 0.f;
    if (act) {
        short8 afr[4];
        if (bf) {
            const short8* ar = (const short8*)((const uint16_t*)tokens + mrow * F_);
#pragma unroll
            for (int c = 0; c < 4; ++c) afr[c] = ar[c * 4 + q];
        } else {
            const float* ar = (const float*)tokens + mrow * F_;
#pragma unroll
            for (int c = 0; c < 4; ++c)
#pragma unroll
                for (int j = 0; j < 8; ++j) afr[c][j] = to_bf(ar[c * 32 + q * 8 + j]);
        }
#pragma unroll
        for (int c = 0; c < 4; ++c) {
            accM = __builtin_amdgcn_mfma_f32_16x16x32_bf16(afr[c], Bfr[(c * 5 + 4) * 64 + l], accM, 0, 0, 0);
#pragma unroll
            for (int nt = 0; nt < 4; ++nt)
                acc1[nt] = __builtin_amdgcn_mfma_f32_16x16x32_bf16(afr[c], Bfr[(c * 5 + nt) * 64 + l], acc1[nt], 0, 0, 0);
        }
        int ccnt = 0;
#pragma unroll
        for (int r = 0; r < 4; ++r) {
            int row = q * 4 + r;
            if (row < T_ && m < T_ && accM[r] >= TH_INNER) ccnt++;
        }
        ccnt += __shfl_xor(ccnt, 16);
        ccnt += __shfl_xor(ccnt, 32);
        float deg = 1.f + (float)ccnt;
        istc = 1.f / sqrtf(deg);
        if (q == 0 && m < T_) { ist_s[m] = istc; idt_s[m] = 1.f / deg; }
#pragma unroll
        for (int nt = 0; nt < 4; ++nt)
#pragma unroll
            for (int r = 0; r < 4; ++r) {
                int row = q * 4 + r;
                if (row < T_) htbuf[row * 64 + nt * 16 + m] = acc1[nt][r];
            }
    }
    __syncthreads();
    if (act && m < T_) {
#pragma unroll
        for (int r = 0; r < 4; ++r) {
            int row = q * 4 + r;
            if (row < T_)
                nm[row * 16 + m] = (accM[r] >= TH_INNER) ? ist_s[row] * istc : 0.f;
        }
    }
    __syncthreads();
    if (act) {
        float htc[T_];
#pragma unroll
        for (int s = 0; s < T_; ++s) htc[s] = htbuf[s * 64 + l];
        float b1f = ld1(b1, l, bf);
#pragma unroll
        for (int tt = 0; tt < T_; ++tt) {
            float a = htc[tt] * idt_s[tt] + b1f;
#pragma unroll
            for (int s = 0; s < T_; ++s) a += nm[tt * 16 + s] * htc[s];
            a = (a >= 0.f) ? a : 0.01f * a;
            h1s[tt * 64 + l] = a;
            float v = ist_s[tt] * htc[tt];        // P1 row -> y1[BN+1+tt]
            float vh = __shfl(v, l + 1);
            if ((l & 1) == 0) y1[(size_t)(BN + 1 + tt) * 32 + (l >> 1)] = pack_bf2(v, vh);
        }
    }
    __syncthreads();
    if (act) {
        short8 a2fr[2];
#pragma unroll
        for (int c = 0; c < 2; ++c)
#pragma unroll
            for (int j = 0; j < 8; ++j) a2fr[c][j] = to_bf(h1s[mrow * 64 + c * 32 + q * 8 + j]);
        f32x4 acc2[4] = {};
#pragma unroll
        for (int nt = 0; nt < 4; ++nt)
#pragma unroll
            for (int c = 0; c < 2; ++c)
                acc2[nt] = __builtin_amdgcn_mfma_f32_16x16x32_bf16(a2fr[c], Bfr2[(c * 4 + nt) * 64 + l], acc2[nt], 0, 0, 0);
#pragma unroll
        for (int nt = 0; nt < 4; ++nt)
#pragma unroll
            for (int r = 0; r < 4; ++r) {
                int row = q * 4 + r;
                if (row < T_) htbuf[row * 64 + nt * 16 + m] = acc2[nt][r];
            }
    }
    __syncthreads();
    if (act) {
        float htc[T_];
#pragma unroll
        for (int s = 0; s < T_; ++s) htc[s] = htbuf[s * 64 + l];
        float b2f = ld1(b2, l, bf);
        float ts = 0.f;
#pragma unroll
        for (int tt = 0; tt < T_; ++tt) {
            float o = htc[tt] * idt_s[tt] + b2f;
#pragma unroll
            for (int s = 0; s < T_; ++s) o += nm[tt * 16 + s] * htc[s];
            ts += o;
            float v = ist_s[tt] * htc[tt];        // P2 row -> y2[BN+1+tt]
            float vh = __shfl(v, l + 1);
            if ((l & 1) == 0) y2[(size_t)(BN + 1 + tt) * 32 + (l >> 1)] = pack_bf2(v, vh);
        }
        tok_sum[l] = ts;
    }
}

#define NROWS (N_ + 12)   // graph rows + pad + 10 token P rows (+1 slack)

// stage one graph's y-slice (+token rows) into LDS with group-XOR swizzle
__device__ __forceinline__ void stage_slice(uint32_t* __restrict__ ys,
                                            const uint32_t* __restrict__ yg,
                                            const uint32_t* __restrict__ yall,
                                            int tid) {
#pragma unroll
    for (int it = 0; it < 9; ++it) {
        int idx = it * 1024 + tid;
        if (idx < NROWS * 8) {
            int r = idx >> 3, gg = idx & 7;
            const uint32_t* sp = (r < N_) ? (yg + r * 32)
                                          : (yall + (size_t)(BN + (r - N_)) * 32);
            *(uint4*)&ys[r * 32 + ((gg ^ (r & 7)) << 2)] = *(const uint4*)(sp + gg * 4);
        }
    }
}

// swizzled whole-row read: group owns row 'r', lane part 'wp' reads 16B chunk
__device__ __forceinline__ void row_add(const uint32_t* __restrict__ ys,
                                        int r, int wp, float a[8]) {
    uint4 u = *(const uint4*)&ys[r * 32 + (((wp ^ (r & 7)) & 7) << 2)];
    a[0] += bflo(u.x); a[1] += bfhi(u.x);
    a[2] += bflo(u.y); a[3] += bfhi(u.y);
    a[4] += bflo(u.z); a[5] += bfhi(u.z);
    a[6] += bflo(u.w); a[7] += bfhi(u.w);
}

// one quarter-segment gather (exec-mask handles divergent counts across groups)
__device__ __forceinline__ void gather_seg(const uint32_t* __restrict__ ys,
                                           const int* __restrict__ bp, int cn,
                                           int wp, float a[8]) {
    int nid0 = (cn > 0) ? bp[0] : 0;
    int nid1 = (cn > 1) ? bp[1] : 0;
    for (int e = 0; e < cn; ++e) {
        int curN = nid0;
        nid0 = nid1;
        if (e + 2 < cn) nid1 = bp[e + 2];
        row_add(ys, curN & (N_ - 1), wp, a);
    }
}

// group-mode gather over 4 fixed-stride segments + tokens + self
__device__ __forceinline__ void gather_grp4(const uint32_t* __restrict__ ys,
                                            const int* __restrict__ bucket4,
                                            int node_g, int s0, int s1, int s2, int s3,
                                            int msk_g, int self_l, int wp, float a[8]) {
#pragma unroll
    for (int j = 0; j < 8; ++j) a[j] = 0.f;
    const int* bp = bucket4 + (size_t)node_g * (4 * SLOTS);
    gather_seg(ys, bp, s0, wp, a);
    gather_seg(ys, bp + SLOTS, s1, wp, a);
    gather_seg(ys, bp + 2 * SLOTS, s2, wp, a);
    gather_seg(ys, bp + 3 * SLOTS, s3, wp, a);
    unsigned mm = (unsigned)msk_g;                // virtual token edges from LDS rows
    while (mm) {
        int tk = __ffs(mm) - 1;
        mm &= mm - 1;
        row_add(ys, N_ + 1 + tk, wp, a);
    }
    row_add(ys, self_l, wp, a);                   // self loop
}

// ---- launch 3: layer1 (LDS-staged group gather + fused h1@W2 -> y2) ----
__global__ __launch_bounds__(1024, 1) void k_layer1(const uint32_t* __restrict__ y1,
                                                    const float* __restrict__ inv_s,
                                                    const int* __restrict__ cnt4t,
                                                    const int* __restrict__ maskA,
                                                    const int* __restrict__ bucket4,
                                                    const void* __restrict__ b1,
                                                    const short8* __restrict__ Bfr2,
                                                    const int* __restrict__ flag,
                                                    uint32_t* __restrict__ y2) {
    __shared__ uint32_t y1s[NROWS * 32];         // 129.5 KB staged slice (swizzled)
    __shared__ uint32_t h1w[16][9 * 36];         // bf16-packed h1 tiles; row 8 = zeros
    int bf = *flag;
    int tid = threadIdx.x;
    int lane = tid & 63, wv = tid >> 6;
    int gi = lane >> 3, wp = lane & 7;
    int g = blockIdx.x & 63, c = blockIdx.x >> 6;   // 4 blocks/graph, same XCD
    stage_slice(y1s, y1 + (size_t)g * N_ * 32, y1, tid);
    int nbase = g * N_ + c * 256 + wv * 16;
    int ln16 = lane & 15;
    uint4 c4 = *(const uint4*)&cnt4t[(nbase + ln16) * 4];
    int c4x = (int)c4.x, c4y = (int)c4.y, c4z = (int)c4.z, c4w = (int)c4.w;
    float isvv = inv_s[nbase + ln16];
    int mskv = maskA[nbase + ln16];
    float bc[8];
#pragma unroll
    for (int j = 0; j < 8; ++j) bc[j] = ld1(b1, wp * 8 + j, bf);
    if (lane < 36) h1w[wv][8 * 36 + lane] = 0;   // zero row for A-frag rows 8..15
    __syncthreads();
    int m = lane & 15, q = lane >> 4;
    int mr = (m < 8) ? m : 8;
    for (int k = 0; k < 2; ++k) {
        int ni = k * 8 + gi;
        int s0 = __shfl(c4x, ni), s1 = __shfl(c4y, ni);
        int s2 = __shfl(c4z, ni), s3 = __shfl(c4w, ni);
        int msk_g = __shfl(mskv, ni);
        float is_g = __shfl(isvv, ni);
        int self_l = c * 256 + wv * 16 + ni;
        float a[8];
        gather_grp4(y1s, bucket4, nbase + ni, s0, s1, s2, s3, msk_g, self_l, wp, a);
        uint32_t pk[4];
#pragma unroll
        for (int j = 0; j < 4; ++j) {
            float h0 = a[2 * j] * is_g + bc[2 * j];
            float h1v = a[2 * j + 1] * is_g + bc[2 * j + 1];
            h0 = (h0 >= 0.f) ? h0 : 0.01f * h0;
            h1v = (h1v >= 0.f) ? h1v : 0.01f * h1v;
            pk[j] = pack_bf2(h0, h1v);
        }
#pragma unroll
        for (int j = 0; j < 4; ++j) h1w[wv][gi * 36 + wp * 4 + j] = pk[j];
        short8 afr[2];
#pragma unroll
        for (int cc = 0; cc < 2; ++cc)
            afr[cc] = *(const short8*)&h1w[wv][mr * 36 + cc * 16 + q * 4];
        f32x4 acc[4] = {};
#pragma unroll
        for (int nt = 0; nt < 4; ++nt)
#pragma unroll
            for (int cc = 0; cc < 2; ++cc)
                acc[nt] = __builtin_amdgcn_mfma_f32_16x16x32_bf16(afr[cc], Bfr2[(cc * 4 + nt) * 64 + lane], acc[nt], 0, 0, 0);
#pragma unroll
        for (int r = 0; r < 4; ++r) {
            int tr = q * 4 + r;
            if (tr < 8) {
                int node = nbase + k * 8 + tr;
                float is = __shfl(isvv, k * 8 + tr);
#pragma unroll
                for (int nt = 0; nt < 4; ++nt) {
                    float v = acc[nt][r] * is;
                    float vh = __shfl(v, lane + 1);
                    if ((m & 1) == 0)
                        y2[(size_t)node * 32 + nt * 8 + (m >> 1)] = pack_bf2(v, vh);
                }
            }
        }
    }
}

// ---- launch 4: layer2 + pooling + fence-free ticket -> answering head ----
__global__ __launch_bounds__(1024, 1) void k_layer2f(const uint32_t* __restrict__ y2,
                                                     const float* __restrict__ inv_s,
                                                     const int* __restrict__ cnt4t,
                                                     const int* __restrict__ maskA,
                                                     const int* __restrict__ bucket4,
                                                     const void* __restrict__ b2,
                                                     const int* __restrict__ flag,
                                                     float* __restrict__ graph_sum,
                                                     int* __restrict__ done,
                                                     const float* __restrict__ tok_sum,
                                                     const void* __restrict__ Wa,
                                                     const void* __restrict__ ba,
                                                     void* __restrict__ out) {
    __shared__ uint32_t y2s[NROWS * 32];         // 129.5 KB staged slice (swizzled)
    __shared__ float pool[16][64];
    __shared__ int ticket_s;
    int bf = *flag;
    int tid = threadIdx.x;
    int lane = tid & 63, wv = tid >> 6;
    int gi = lane >> 3, wp = lane & 7;
    int g = blockIdx.x & 63, c = blockIdx.x >> 6;
    stage_slice(y2s, y2 + (size_t)g * N_ * 32, y2, tid);
    int nbase = g * N_ + c * 256 + wv * 16;
    int ln16 = lane & 15;
    uint4 c4 = *(const uint4*)&cnt4t[(nbase + ln16) * 4];
    int c4x = (int)c4.x, c4y = (int)c4.y, c4z = (int)c4.z, c4w = (int)c4.w;
    float isvv = inv_s[nbase + ln16];
    int mskv = maskA[nbase + ln16];
    float bc[8];
#pragma unroll
    for (int j = 0; j < 8; ++j) bc[j] = ld1(b2, wp * 8 + j, bf);
    __syncthreads();
    float p[8];
#pragma unroll
    for (int j = 0; j < 8; ++j) p[j] = 0.f;
    for (int k = 0; k < 2; ++k) {
        int ni = k * 8 + gi;
        int s0 = __shfl(c4x, ni), s1 = __shfl(c4y, ni);
        int s2 = __shfl(c4z, ni), s3 = __shfl(c4w, ni);
        int msk_g = __shfl(mskv, ni);
        float is_g = __shfl(isvv, ni);
        int self_l = c * 256 + wv * 16 + ni;
        float a[8];
        gather_grp4(y2s, bucket4, nbase + ni, s0, s1, s2, s3, msk_g, self_l, wp, a);
#pragma unroll
        for (int j = 0; j < 8; ++j) p[j] += a[j] * is_g + bc[j];
    }
#pragma unroll
    for (int j = 0; j < 8; ++j) {                // reduce across the 8 groups
        p[j] += __shfl_xor(p[j], 8);
        p[j] += __shfl_xor(p[j], 16);
        p[j] += __shfl_xor(p[j], 32);
    }
    if (gi == 0) {
#pragma unroll
        for (int j = 0; j < 8; ++j) pool[wv][wp * 8 + j] = p[j];
    }
    __syncthreads();
    if (tid < 64) {
        float s = 0.f;
#pragma unroll
        for (int w2 = 0; w2 < 16; ++w2) s += pool[w2][tid];
        atomicAdd(&graph_sum[g * H_ + tid], s);
    }
    __syncthreads();
    // fence-free ticket: wave 0 drains its atomics (vmcnt), then claims a ticket.
    // graph_sum adds and done ticket are both device-scope atomics at the coherent
    // point; vmcnt(0) orders them without an L2 flush (round-7 lesson).
    if (tid < 64) {
        asm volatile("s_waitcnt vmcnt(0)" ::: "memory");
        if (tid == 0) ticket_s = atomicAdd(&done[g], 1);
    }
    __syncthreads();
    if (ticket_s == 3 && tid < 64) {
        int l = tid;
        float gs = atomicAdd(&graph_sum[g * H_ + l], 0.0f);   // coherent read
        float e = (tok_sum[l] + gs) * (1.0f / 1034.0f);
        float p0 = e * ld1(Wa, l * 2 + 0, bf);
        float p1 = e * ld1(Wa, l * 2 + 1, bf);
#pragma unroll
        for (int d = 32; d >= 1; d >>= 1) {
            p0 += __shfl_xor(p0, d);
            p1 += __shfl_xor(p1, d);
        }
        if (l == 0) {
            float l0 = p0 + ld1(ba, 0, bf);
            float l1 = p1 + ld1(ba, 1, bf);
            float mx = fmaxf(l0, l1);
            float e0 = expf(l0 - mx), e1 = expf(l1 - mx);
            float s = e0 + e1;
            float o0 = e0 / s, o1 = e1 / s;
            if (bf) {
                ((__hip_bfloat16*)out)[g * 2 + 0] = __float2bfloat16(o0);
                ((__hip_bfloat16*)out)[g * 2 + 1] = __float2bfloat16(o1);
            } else {
                ((float*)out)[g * 2 + 0] = o0;
                ((float*)out)[g * 2 + 1] = o1;
            }
        }
    }
}

extern "C" void kernel_launch(void* const* d_in, const int* in_sizes, int n_in,
                              void* d_out, int out_size, void* d_ws, size_t ws_size,
                              hipStream_t stream) {
    (void)in_sizes; (void)n_in; (void)out_size; (void)ws_size;
    const void* x      = d_in[0];
    const void* tokens = d_in[1];
    const void* W1     = d_in[2];
    const void* b1     = d_in[3];
    const void* W2     = d_in[4];
    const void* b2     = d_in[5];
    const void* Wa     = d_in[6];
    const void* ba     = d_in[7];
    const int* esrc = (const int*)d_in[8];
    const int* edst = (const int*)d_in[9];

    char* w = (char*)d_ws;
    auto alloc = [&](size_t bytes) { void* p = (void*)w; w += (bytes + 255) & ~(size_t)255; return p; };
    int*      cnt4t     = (int*)alloc((size_t)BN * 4 * 4);               // [node][quarter]
    int*      maskA     = (int*)alloc(BN * 4);
    float*    inv_s     = (float*)alloc(BN * 4);
    int*      bucket4   = (int*)alloc((size_t)BN * 4 * SLOTS * 4 + 512); // 25 MB fixed-stride CSR
    uint32_t* y1        = (uint32_t*)alloc((size_t)(BN + 12) * 32 * 4);  // node rows + pad + P rows
    uint32_t* y2        = (uint32_t*)alloc((size_t)(BN + 12) * 32 * 4);
    float*    tok_sum   = (float*)alloc(H_ * 4);
    float*    graph_sum = (float*)alloc(B_ * H_ * 4);
    int*      done      = (int*)alloc(B_ * 4);
    short8*   Bfr       = (short8*)alloc(4 * 5 * 64 * sizeof(short8));
    short8*   Bfr2      = (short8*)alloc(2 * 4 * 64 * sizeof(short8));
    int*      dflag     = (int*)alloc(256);

    k_csp     <<<258, 1024, 0, stream>>>(esrc, edst, bucket4, cnt4t, W1, W2, tokens,
                                         dflag, Bfr, Bfr2, graph_sum, done,
                                         y1 + (size_t)BN * 32, y2 + (size_t)BN * 32);
    k_node_tok<<<257, 1024, 0, stream>>>(x, Bfr, Bfr2, cnt4t, dflag, tokens, b1, b2,
                                         y1, y2, tok_sum, inv_s, maskA);
    k_layer1  <<<B_ * 4, 1024, 0, stream>>>(y1, inv_s, cnt4t, maskA, bucket4, b1, Bfr2, dflag, y2);
    k_layer2f <<<B_ * 4, 1024, 0, stream>>>(y2, inv_s, cnt4t, maskA, bucket4, b2, dflag,
                                            graph_sum, done, tok_sum, Wa, ba, d_out);
}

// Round 10
// 156.217 us; speedup vs baseline: 1.0887x; 1.0887x over previous
//
#include <hip/hip_runtime.h>
#include <hip/hip_bf16.h>
#include <stdint.h>

#define B_ 64
#define N_ 1024
#define E_ 16384
#define F_ 128
#define H_ 64
#define T_ 10
#define BN (B_*N_)   // 65536
#define BE (B_*E_)   // 1048576

// sigmoid(z) >= p  <=>  z >= log(p/(1-p))
#define TH_INNER (-0.84729786f)   // logit(0.3)
#define TH_CROSS (-2.1972246f)    // logit(0.1)

typedef __attribute__((ext_vector_type(8))) short short8;  // bf16x8 MFMA frag
typedef __attribute__((ext_vector_type(4))) float f32x4;   // MFMA acc

__device__ __forceinline__ float ld1(const void* p, int i, int bf) {
    if (bf) {
        uint16_t u = ((const uint16_t*)p)[i];
        return __uint_as_float(((uint32_t)u) << 16);
    }
    return ((const float*)p)[i];
}

__device__ __forceinline__ short to_bf(float x) {
    return (short)__bfloat16_as_ushort(__float2bfloat16(x));
}

__device__ __forceinline__ uint32_t pack_bf2(float lo, float hi) {
    uint32_t l = (uint32_t)__bfloat16_as_ushort(__float2bfloat16(lo));
    uint32_t h = (uint32_t)__bfloat16_as_ushort(__float2bfloat16(hi));
    return l | (h << 16);
}

__device__ __forceinline__ float bflo(uint32_t u) { return __uint_as_float(u << 16); }
__device__ __forceinline__ float bfhi(uint32_t u) { return __uint_as_float(u & 0xffff0000u); }

// ---------------- count (256 blocks, per-quarter histograms) + fused W-prep ----------------
__global__ __launch_bounds__(1024) void k_count_prep(const int* __restrict__ dst,
                                                     int* __restrict__ cnt4,
                                                     const void* __restrict__ W1,
                                                     const void* __restrict__ W2,
                                                     const void* __restrict__ tokens,
                                                     int* __restrict__ flag,
                                                     short8* __restrict__ Bfr,
                                                     short8* __restrict__ Bfr2,
                                                     float* __restrict__ gsum,
                                                     uint32_t* __restrict__ y1pad,
                                                     uint32_t* __restrict__ y2pad) {
    __shared__ int lcnt[N_];
    int t = threadIdx.x;
    if (blockIdx.x >= 256) {                     // fused k_prep (blocks 256,257)
        uint32_t du = ((const uint32_t*)tokens)[t & 63];
        float dlo = __uint_as_float(du << 16);
        unsigned long long vote = __ballot(fabsf(dlo) <= 1.0f);
        int bf = (vote == ~0ull) ? 1 : 0;
        if (blockIdx.x == 256 && t == 0) *flag = bf;
        int f = (int)(blockIdx.x - 256) * 1024 + t;   // [0, 2048)
        if (f < 1280) {                          // Bfr: [128 x 80] = W1 | tokens^T
            int c = f / 320, rem = f % 320;
            int nt = rem / 64, lane = rem % 64;
            int q = lane >> 4, n = nt * 16 + (lane & 15);
            int k0 = c * 32 + q * 8;
            short8 v;
#pragma unroll
            for (int j = 0; j < 8; ++j) {
                int k = k0 + j;
                float x = 0.f;
                if (n < H_) x = ld1(W1, k * H_ + n, bf);
                else if (n < H_ + T_) x = ld1(tokens, (n - H_) * F_ + k, bf);
                v[j] = to_bf(x);
            }
            Bfr[f] = v;
        } else if (f < 1792) {                   // Bfr2: W2 [64 x 64]
            int f2 = f - 1280;
            int c = f2 / 256, rem = f2 % 256;
            int nt = rem / 64, lane = rem % 64;
            int q = lane >> 4, n = nt * 16 + (lane & 15);
            int k0 = c * 32 + q * 8;
            short8 v;
#pragma unroll
            for (int j = 0; j < 8; ++j) v[j] = to_bf(ld1(W2, (k0 + j) * H_ + n, bf));
            Bfr2[f2] = v;
        }
        return;
    }
    int g = blockIdx.x & 63, c = blockIdx.x >> 6;   // 4 quarter-blocks per graph
    lcnt[t] = 0;
    if (c == 0 && t < 64) gsum[g * 64 + t] = 0.f;   // zero pool row
    if (blockIdx.x == 0) {                          // zero pad rows once
        if (t < 32) y1pad[t] = 0;
        else if (t < 64) y2pad[t - 32] = 0;
    }
    __syncthreads();
#pragma unroll
    for (int it = 0; it < 4; ++it)
        atomicAdd(&lcnt[dst[g * E_ + c * 4096 + it * 1024 + t]], 1);
    __syncthreads();
    cnt4[c * BN + g * N_ + t] = lcnt[t];
}

// ---------------- scan (64 blocks): totals + quarter bases; block 64 = fused k_tok ----------------
__global__ __launch_bounds__(1024) void k_scan_tok(const int* __restrict__ cnt4,
                                                   int* __restrict__ cnt,
                                                   int* __restrict__ offs,
                                                   int* __restrict__ base4,
                                                   const void* __restrict__ tokens,
                                                   const void* __restrict__ b1,
                                                   const void* __restrict__ b2,
                                                   const short8* __restrict__ Bfr,
                                                   const short8* __restrict__ Bfr2,
                                                   const int* __restrict__ flag,
                                                   uint32_t* __restrict__ y1,
                                                   uint32_t* __restrict__ y2,
                                                   float* __restrict__ tok_sum) {
    __shared__ int wsum[16];
    __shared__ float nm[T_ * 16];
    __shared__ float ist_s[16], idt_s[16];
    __shared__ float htbuf[T_ * 64];
    __shared__ float h1s[T_ * 64];
    int t = threadIdx.x;
    if (blockIdx.x < 64) {                       // ---- scan path ----
        int g = blockIdx.x;
        int c0 = cnt4[0 * BN + g * N_ + t];
        int c1 = cnt4[1 * BN + g * N_ + t];
        int c2 = cnt4[2 * BN + g * N_ + t];
        int c3 = cnt4[3 * BN + g * N_ + t];
        int v = c0 + c1 + c2 + c3;
        int sc = v;                              // wave-level inclusive scan
#pragma unroll
        for (int d = 1; d < 64; d <<= 1) {
            int u = __shfl_up(sc, d);
            if ((t & 63) >= d) sc += u;
        }
        if ((t & 63) == 63) wsum[t >> 6] = sc;
        __syncthreads();
        if (t < 16) {
            int wsc = wsum[t];
#pragma unroll
            for (int d = 1; d < 16; d <<= 1) {
                int u = __shfl_up(wsc, d);
                if (t >= d) wsc += u;
            }
            wsum[t] = wsc;
        }
        __syncthreads();
        int base = sc - v + ((t >= 64) ? wsum[(t >> 6) - 1] : 0);
        int o = g * E_ + base;
        cnt[g * N_ + t] = v;
        offs[g * N_ + t] = o;
        base4[0 * BN + g * N_ + t] = o;
        base4[1 * BN + g * N_ + t] = o + c0;
        base4[2 * BN + g * N_ + t] = o + c0 + c1;
        base4[3 * BN + g * N_ + t] = o + c0 + c1 + c2;
        return;
    }
    // ---- tok path (block 64): wave 0 computes, all waves share barriers ----
    int bf = *flag;
    int l = t;
    bool act = (l < 64);                         // wave-uniform guard
    int m = l & 15, q = (l & 63) >> 4;
    int mrow = (m < T_) ? m : (T_ - 1);
    f32x4 accM = {};
    f32x4 acc1[4] = {};
    float istc = 0.f;
    if (act) {
        short8 afr[4];
        if (bf) {
            const short8* ar = (const short8*)((const uint16_t*)tokens + mrow * F_);
#pragma unroll
            for (int c = 0; c < 4; ++c) afr[c] = ar[c * 4 + q];
        } else {
            const float* ar = (const float*)tokens + mrow * F_;
#pragma unroll
            for (int c = 0; c < 4; ++c)
#pragma unroll
                for (int j = 0; j < 8; ++j) afr[c][j] = to_bf(ar[c * 32 + q * 8 + j]);
        }
#pragma unroll
        for (int c = 0; c < 4; ++c) {
            accM = __builtin_amdgcn_mfma_f32_16x16x32_bf16(afr[c], Bfr[(c * 5 + 4) * 64 + l], accM, 0, 0, 0);
#pragma unroll
            for (int nt = 0; nt < 4; ++nt)
                acc1[nt] = __builtin_amdgcn_mfma_f32_16x16x32_bf16(afr[c], Bfr[(c * 5 + nt) * 64 + l], acc1[nt], 0, 0, 0);
        }
        int ccnt = 0;
#pragma unroll
        for (int r = 0; r < 4; ++r) {
            int row = q * 4 + r;
            if (row < T_ && m < T_ && accM[r] >= TH_INNER) ccnt++;
        }
        ccnt += __shfl_xor(ccnt, 16);
        ccnt += __shfl_xor(ccnt, 32);
        float deg = 1.f + (float)ccnt;
        istc = 1.f / sqrtf(deg);
        if (q == 0 && m < T_) { ist_s[m] = istc; idt_s[m] = 1.f / deg; }
#pragma unroll
        for (int nt = 0; nt < 4; ++nt)
#pragma unroll
            for (int r = 0; r < 4; ++r) {
                int row = q * 4 + r;
                if (row < T_) htbuf[row * 64 + nt * 16 + m] = acc1[nt][r];
            }
    }
    __syncthreads();
    if (act && m < T_) {
#pragma unroll
        for (int r = 0; r < 4; ++r) {
            int row = q * 4 + r;
            if (row < T_)
                nm[row * 16 + m] = (accM[r] >= TH_INNER) ? ist_s[row] * istc : 0.f;
        }
    }
    __syncthreads();
    if (act) {
        float htc[T_];
#pragma unroll
        for (int s = 0; s < T_; ++s) htc[s] = htbuf[s * 64 + l];
        float b1f = ld1(b1, l, bf);
#pragma unroll
        for (int tt = 0; tt < T_; ++tt) {
            float a = htc[tt] * idt_s[tt] + b1f;
#pragma unroll
            for (int s = 0; s < T_; ++s) a += nm[tt * 16 + s] * htc[s];
            a = (a >= 0.f) ? a : 0.01f * a;
            h1s[tt * 64 + l] = a;
            float v = ist_s[tt] * htc[tt];        // P1 row -> y1[BN+1+tt]
            float vh = __shfl(v, l + 1);
            if ((l & 1) == 0) y1[(size_t)(BN + 1 + tt) * 32 + (l >> 1)] = pack_bf2(v, vh);
        }
    }
    __syncthreads();
    if (act) {
        short8 a2fr[2];
#pragma unroll
        for (int c = 0; c < 2; ++c)
#pragma unroll
            for (int j = 0; j < 8; ++j) a2fr[c][j] = to_bf(h1s[mrow * 64 + c * 32 + q * 8 + j]);
        f32x4 acc2[4] = {};
#pragma unroll
        for (int nt = 0; nt < 4; ++nt)
#pragma unroll
            for (int c = 0; c < 2; ++c)
                acc2[nt] = __builtin_amdgcn_mfma_f32_16x16x32_bf16(a2fr[c], Bfr2[(c * 4 + nt) * 64 + l], acc2[nt], 0, 0, 0);
#pragma unroll
        for (int nt = 0; nt < 4; ++nt)
#pragma unroll
            for (int r = 0; r < 4; ++r) {
                int row = q * 4 + r;
                if (row < T_) htbuf[row * 64 + nt * 16 + m] = acc2[nt][r];
            }
    }
    __syncthreads();
    if (act) {
        float htc[T_];
#pragma unroll
        for (int s = 0; s < T_; ++s) htc[s] = htbuf[s * 64 + l];
        float b2f = ld1(b2, l, bf);
        float ts = 0.f;
#pragma unroll
        for (int tt = 0; tt < T_; ++tt) {
            float o = htc[tt] * idt_s[tt] + b2f;
#pragma unroll
            for (int s = 0; s < T_; ++s) o += nm[tt * 16 + s] * htc[s];
            ts += o;
            float v = ist_s[tt] * htc[tt];        // P2 row -> y2[BN+1+tt]
            float vh = __shfl(v, l + 1);
            if ((l & 1) == 0) y2[(size_t)(BN + 1 + tt) * 32 + (l >> 1)] = pack_bf2(v, vh);
        }
        tok_sum[l] = ts;
    }
}

// ---------------- scatter (blocks 0..255) | node GEMM (blocks 256..511) ----------------
__global__ __launch_bounds__(1024) void k_scatter_node(const int* __restrict__ src,
                                                       const int* __restrict__ dst,
                                                       const int* __restrict__ base4,
                                                       int* __restrict__ bucket,
                                                       const void* __restrict__ x,
                                                       const short8* __restrict__ Bfr,
                                                       const int* __restrict__ cnt,
                                                       const int* __restrict__ flag,
                                                       uint32_t* __restrict__ y1,
                                                       float* __restrict__ inv_s,
                                                       int* __restrict__ maskA) {
    __shared__ int cur[N_];
    int t = threadIdx.x;
    if (blockIdx.x < 256) {                      // ---- scatter ----
        int g = blockIdx.x & 63, c = blockIdx.x >> 6;
        cur[t] = base4[c * BN + g * N_ + t];
        __syncthreads();
#pragma unroll
        for (int it = 0; it < 4; ++it) {
            int i = g * E_ + c * 4096 + it * 1024 + t;
            int d = dst[i];
            int p = atomicAdd(&cur[d], 1);
            bucket[p] = g * N_ + src[i];
        }
        return;
    }
    // ---- node GEMM (16 waves/block, 256 rows/block) ----
    int bid = blockIdx.x - 256;
    int bf = *flag;
    int lane = t & 63, w16 = t >> 6;
    int g = bid & 63, c = bid >> 6;              // XCD swizzle
    int row0 = g * N_ + c * 256 + w16 * 16;
    int m = lane & 15, q = lane >> 4;
    int row = row0 + m;
    short8 afr[4];
    if (bf) {
        const short8* ar = (const short8*)((const uint16_t*)x + (size_t)row * F_);
#pragma unroll
        for (int cc = 0; cc < 4; ++cc) afr[cc] = ar[cc * 4 + q];
    } else {
        const float* ar = (const float*)x + (size_t)row * F_;
#pragma unroll
        for (int cc = 0; cc < 4; ++cc)
#pragma unroll
            for (int j = 0; j < 8; ++j)
                afr[cc][j] = to_bf(ar[cc * 32 + q * 8 + j]);
    }
    f32x4 acc[5] = {};
#pragma unroll
    for (int nt = 0; nt < 5; ++nt)
#pragma unroll
        for (int cc = 0; cc < 4; ++cc) {
            short8 bfr = Bfr[(cc * 5 + nt) * 64 + lane];
            acc[nt] = __builtin_amdgcn_mfma_f32_16x16x32_bf16(afr[cc], bfr, acc[nt], 0, 0, 0);
        }
    unsigned long long bal[4];
#pragma unroll
    for (int r = 0; r < 4; ++r) {
        int pred = (m < T_) && (acc[4][r] >= TH_CROSS);
        bal[r] = __ballot(pred);
    }
    float isv[4];
#pragma unroll
    for (int r = 0; r < 4; ++r) {
        int node = row0 + q * 4 + r;
        int mk = (int)((bal[r] >> (q * 16)) & 0x3FF);
        int ec = cnt[node];
        int pc = __popc((unsigned)mk);
        float deg = 1.f + (float)ec + (float)pc;
        isv[r] = 1.f / sqrtf(deg);
        if (m == 0) { inv_s[node] = isv[r]; maskA[node] = mk; }
    }
#pragma unroll
    for (int r = 0; r < 4; ++r) {
        int node = row0 + q * 4 + r;
#pragma unroll
        for (int nt = 0; nt < 4; ++nt) {
            float v = acc[nt][r] * isv[r];
            float vh = __shfl(v, lane + 1);
            if ((m & 1) == 0)
                y1[(size_t)node * 32 + nt * 8 + (m >> 1)] = pack_bf2(v, vh);
        }
    }
}

#define NROWS (N_ + 12)   // graph rows + pad + 10 token P rows (+1 slack)

// stage one graph's y-slice (+token rows) into LDS with group-XOR swizzle
__device__ __forceinline__ void stage_slice(uint32_t* __restrict__ ys,
                                            const uint32_t* __restrict__ yg,
                                            const uint32_t* __restrict__ yall,
                                            int tid) {
#pragma unroll
    for (int it = 0; it < 9; ++it) {
        int idx = it * 1024 + tid;
        if (idx < NROWS * 8) {
            int r = idx >> 3, gg = idx & 7;
            const uint32_t* sp = (r < N_) ? (yg + r * 32)
                                          : (yall + (size_t)(BN + (r - N_)) * 32);
            *(uint4*)&ys[r * 32 + ((gg ^ (r & 7)) << 2)] = *(const uint4*)(sp + gg * 4);
        }
    }
}

// swizzled whole-row read: group owns row 'r', lane part 'wp' reads 16B chunk
__device__ __forceinline__ void row_add(const uint32_t* __restrict__ ys,
                                        int r, int wp, float a[8]) {
    uint4 u = *(const uint4*)&ys[r * 32 + (((wp ^ (r & 7)) & 7) << 2)];
    a[0] += bflo(u.x); a[1] += bfhi(u.x);
    a[2] += bflo(u.y); a[3] += bfhi(u.y);
    a[4] += bflo(u.z); a[5] += bfhi(u.z);
    a[6] += bflo(u.w); a[7] += bfhi(u.w);
}

// group-mode gather: 8-lane group owns one node, reads whole rows from LDS.
// loop bound is per-group cnt_g; exec-mask divergence handles unequal counts
// (r9-verified pattern; saves the explicit wave-max shuffles of r8).
__device__ __forceinline__ void gather_grp(const uint32_t* __restrict__ ys,
                                           const int* __restrict__ bucket,
                                           int cnt_g, int off_g, int msk_g, int self_l,
                                           int wp, float a[8]) {
#pragma unroll
    for (int j = 0; j < 8; ++j) a[j] = 0.f;
    int nid0 = (cnt_g > 0) ? bucket[off_g] : 0;
    int nid1 = (cnt_g > 1) ? bucket[off_g + 1] : 0;
    for (int e = 0; e < cnt_g; ++e) {
        int curN = nid0;
        nid0 = nid1;
        if (e + 2 < cnt_g) nid1 = bucket[off_g + e + 2];
        row_add(ys, curN & (N_ - 1), wp, a);
    }
    unsigned mm = (unsigned)msk_g;                // virtual token edges from LDS rows
    while (mm) {
        int tk = __ffs(mm) - 1;
        mm &= mm - 1;
        row_add(ys, N_ + 1 + tk, wp, a);
    }
    row_add(ys, self_l, wp, a);                   // self loop
}

// ---------------- layer1: LDS-staged group gather + fused h1@W2 -> y2 ----------------
__global__ __launch_bounds__(1024, 1) void k_layer1(const uint32_t* __restrict__ y1,
                                                    const float* __restrict__ inv_s,
                                                    const int* __restrict__ cnt,
                                                    const int* __restrict__ offs,
                                                    const int* __restrict__ maskA,
                                                    const int* __restrict__ bucket,
                                                    const void* __restrict__ b1,
                                                    const short8* __restrict__ Bfr2,
                                                    const int* __restrict__ flag,
                                                    uint32_t* __restrict__ y2) {
    __shared__ uint32_t y1s[NROWS * 32];         // 129.5 KB staged slice (swizzled)
    __shared__ uint32_t h1w[16][9 * 36];         // bf16-packed h1 tiles; row 8 = zeros
    int bf = *flag;
    int tid = threadIdx.x;
    int lane = tid & 63, wv = tid >> 6;
    int gi = lane >> 3, wp = lane & 7;
    int g = blockIdx.x & 63, c = blockIdx.x >> 6;   // 4 blocks/graph, same XCD
    stage_slice(y1s, y1 + (size_t)g * N_ * 32, y1, tid);
    int nbase = g * N_ + c * 256 + wv * 16;
    int ln16 = lane & 15;
    int cntv = cnt[nbase + ln16];
    int offv = offs[nbase + ln16];
    float isvv = inv_s[nbase + ln16];
    int mskv = maskA[nbase + ln16];
    float bc[8];
#pragma unroll
    for (int j = 0; j < 8; ++j) bc[j] = ld1(b1, wp * 8 + j, bf);
    if (lane < 36) h1w[wv][8 * 36 + lane] = 0;   // zero row for A-frag rows 8..15
    __syncthreads();
    int m = lane & 15, q = lane >> 4;
    int mr = (m < 8) ? m : 8;
    for (int k = 0; k < 2; ++k) {
        int ni = k * 8 + gi;
        int cnt_g = __shfl(cntv, ni);
        int off_g = __shfl(offv, ni);
        int msk_g = __shfl(mskv, ni);
        float is_g = __shfl(isvv, ni);
        float a[8];
        gather_grp(y1s, bucket, cnt_g, off_g, msk_g, c * 256 + wv * 16 + ni, wp, a);
        uint32_t pk[4];
#pragma unroll
        for (int j = 0; j < 4; ++j) {
            float h0 = a[2 * j] * is_g + bc[2 * j];
            float h1v = a[2 * j + 1] * is_g + bc[2 * j + 1];
            h0 = (h0 >= 0.f) ? h0 : 0.01f * h0;
            h1v = (h1v >= 0.f) ? h1v : 0.01f * h1v;
            pk[j] = pack_bf2(h0, h1v);
        }
#pragma unroll
        for (int j = 0; j < 4; ++j) h1w[wv][gi * 36 + wp * 4 + j] = pk[j];
        short8 afr[2];
#pragma unroll
        for (int cc = 0; cc < 2; ++cc)
            afr[cc] = *(const short8*)&h1w[wv][mr * 36 + cc * 16 + q * 4];
        f32x4 acc[4] = {};
#pragma unroll
        for (int nt = 0; nt < 4; ++nt)
#pragma unroll
            for (int cc = 0; cc < 2; ++cc)
                acc[nt] = __builtin_amdgcn_mfma_f32_16x16x32_bf16(afr[cc], Bfr2[(cc * 4 + nt) * 64 + lane], acc[nt], 0, 0, 0);
#pragma unroll
        for (int r = 0; r < 4; ++r) {
            int tr = q * 4 + r;
            if (tr < 8) {
                int node = nbase + k * 8 + tr;
                float is = __shfl(isvv, k * 8 + tr);
#pragma unroll
                for (int nt = 0; nt < 4; ++nt) {
                    float v = acc[nt][r] * is;
                    float vh = __shfl(v, lane + 1);
                    if ((m & 1) == 0)
                        y2[(size_t)node * 32 + nt * 8 + (m >> 1)] = pack_bf2(v, vh);
                }
            }
        }
    }
}

// ---------------- layer2: LDS-staged group gather + pooling ----------------
__global__ __launch_bounds__(1024, 1) void k_layer2(const uint32_t* __restrict__ y2,
                                                    const float* __restrict__ inv_s,
                                                    const int* __restrict__ cnt,
                                                    const int* __restrict__ offs,
                                                    const int* __restrict__ maskA,
                                                    const int* __restrict__ bucket,
                                                    const void* __restrict__ b2,
                                                    const int* __restrict__ flag,
                                                    float* __restrict__ graph_sum) {
    __shared__ uint32_t y2s[NROWS * 32];         // 129.5 KB staged slice (swizzled)
    __shared__ float pool[16][64];
    int bf = *flag;
    int tid = threadIdx.x;
    int lane = tid & 63, wv = tid >> 6;
    int gi = lane >> 3, wp = lane & 7;
    int g = blockIdx.x & 63, c = blockIdx.x >> 6;
    stage_slice(y2s, y2 + (size_t)g * N_ * 32, y2, tid);
    int nbase = g * N_ + c * 256 + wv * 16;
    int ln16 = lane & 15;
    int cntv = cnt[nbase + ln16];
    int offv = offs[nbase + ln16];
    float isvv = inv_s[nbase + ln16];
    int mskv = maskA[nbase + ln16];
    float bc[8];
#pragma unroll
    for (int j = 0; j < 8; ++j) bc[j] = ld1(b2, wp * 8 + j, bf);
    __syncthreads();
    float p[8];
#pragma unroll
    for (int j = 0; j < 8; ++j) p[j] = 0.f;
    for (int k = 0; k < 2; ++k) {
        int ni = k * 8 + gi;
        int cnt_g = __shfl(cntv, ni);
        int off_g = __shfl(offv, ni);
        int msk_g = __shfl(mskv, ni);
        float is_g = __shfl(isvv, ni);
        float a[8];
        gather_grp(y2s, bucket, cnt_g, off_g, msk_g, c * 256 + wv * 16 + ni, wp, a);
#pragma unroll
        for (int j = 0; j < 8; ++j) p[j] += a[j] * is_g + bc[j];
    }
#pragma unroll
    for (int j = 0; j < 8; ++j) {                // reduce across the 8 groups
        p[j] += __shfl_xor(p[j], 8);
        p[j] += __shfl_xor(p[j], 16);
        p[j] += __shfl_xor(p[j], 32);
    }
    if (gi == 0) {
#pragma unroll
        for (int j = 0; j < 8; ++j) pool[wv][wp * 8 + j] = p[j];
    }
    __syncthreads();
    if (tid < 64) {
        float s = 0.f;
#pragma unroll
        for (int w2 = 0; w2 < 16; ++w2) s += pool[w2][tid];
        atomicAdd(&graph_sum[g * H_ + tid], s);
    }
}

// ---------------- pooled emb -> answering head -> softmax ----------------
__global__ __launch_bounds__(64) void k_final(const float* __restrict__ graph_sum,
                                              const float* __restrict__ tok_sum,
                                              const void* __restrict__ Wa,
                                              const void* __restrict__ ba,
                                              const int* __restrict__ flag,
                                              void* __restrict__ out) {
    int bf = *flag;
    int b = blockIdx.x, l = threadIdx.x;
    float e = (tok_sum[l] + graph_sum[b * H_ + l]) * (1.0f / 1034.0f);
    float p0 = e * ld1(Wa, l * 2 + 0, bf);
    float p1 = e * ld1(Wa, l * 2 + 1, bf);
#pragma unroll
    for (int d = 32; d >= 1; d >>= 1) {
        p0 += __shfl_xor(p0, d);
        p1 += __shfl_xor(p1, d);
    }
    if (l == 0) {
        float l0 = p0 + ld1(ba, 0, bf);
        float l1 = p1 + ld1(ba, 1, bf);
        float mx = fmaxf(l0, l1);
        float e0 = expf(l0 - mx), e1 = expf(l1 - mx);
        float s = e0 + e1;
        float o0 = e0 / s, o1 = e1 / s;
        if (bf) {
            ((__hip_bfloat16*)out)[b * 2 + 0] = __float2bfloat16(o0);
            ((__hip_bfloat16*)out)[b * 2 + 1] = __float2bfloat16(o1);
        } else {
            ((float*)out)[b * 2 + 0] = o0;
            ((float*)out)[b * 2 + 1] = o1;
        }
    }
}

extern "C" void kernel_launch(void* const* d_in, const int* in_sizes, int n_in,
                              void* d_out, int out_size, void* d_ws, size_t ws_size,
                              hipStream_t stream) {
    (void)in_sizes; (void)n_in; (void)out_size; (void)ws_size;
    const void* x      = d_in[0];
    const void* tokens = d_in[1];
    const void* W1     = d_in[2];
    const void* b1     = d_in[3];
    const void* W2     = d_in[4];
    const void* b2     = d_in[5];
    const void* Wa     = d_in[6];
    const void* ba     = d_in[7];
    const int* esrc = (const int*)d_in[8];
    const int* edst = (const int*)d_in[9];

    char* w = (char*)d_ws;
    auto alloc = [&](size_t bytes) { void* p = (void*)w; w += (bytes + 255) & ~(size_t)255; return p; };
    int*      cnt       = (int*)alloc(BN * 4);
    int*      offs      = (int*)alloc(BN * 4);
    int*      maskA     = (int*)alloc(BN * 4);
    float*    inv_s     = (float*)alloc(BN * 4);
    int*      cnt4      = (int*)alloc((size_t)4 * BN * 4);
    int*      base4     = (int*)alloc((size_t)4 * BN * 4);
    int*      bucket    = (int*)alloc((size_t)BE * 4 + 512);            // 4 MB dense CSR
    uint32_t* y1        = (uint32_t*)alloc((size_t)(BN + 12) * 32 * 4); // node rows + pad + P rows
    uint32_t* y2        = (uint32_t*)alloc((size_t)(BN + 12) * 32 * 4);
    float*    tok_sum   = (float*)alloc(H_ * 4);
    float*    graph_sum = (float*)alloc(B_ * H_ * 4);
    short8*   Bfr       = (short8*)alloc(4 * 5 * 64 * sizeof(short8));
    short8*   Bfr2      = (short8*)alloc(2 * 4 * 64 * sizeof(short8));
    int*      dflag     = (int*)alloc(256);

    k_count_prep  <<<258, 1024, 0, stream>>>(edst, cnt4, W1, W2, tokens, dflag, Bfr, Bfr2,
                                             graph_sum,
                                             y1 + (size_t)BN * 32, y2 + (size_t)BN * 32);
    k_scan_tok    <<<65, 1024, 0, stream>>>(cnt4, cnt, offs, base4, tokens, b1, b2,
                                            Bfr, Bfr2, dflag, y1, y2, tok_sum);
    k_scatter_node<<<512, 1024, 0, stream>>>(esrc, edst, base4, bucket, x, Bfr, cnt,
                                             dflag, y1, inv_s, maskA);
    k_layer1      <<<B_ * 4, 1024, 0, stream>>>(y1, inv_s, cnt, offs, maskA, bucket, b1, Bfr2, dflag, y2);
    k_layer2      <<<B_ * 4, 1024, 0, stream>>>(y2, inv_s, cnt, offs, maskA, bucket, b2, dflag, graph_sum);
    k_final       <<<B_, 64, 0, stream>>>(graph_sum, tok_sum, Wa, ba, dflag, d_out);
}